// Round 5
// baseline (646.225 us; speedup 1.0000x reference)
//
#include <hip/hip_runtime.h>
#include <hip/hip_bf16.h>
#include <stdint.h>

typedef _Float16 f16;
typedef _Float16 f16x8 __attribute__((ext_vector_type(8)));
typedef float f32x4 __attribute__((ext_vector_type(4)));

#define N_FEAT 4096
#define M_ROWS 8192
#define QSTRIDE 512  // IN_FEATURES / 8 codewords per W row

// Async global->LDS, 16B per lane: wave-uniform LDS base, HW adds lane*16.
#define GLD16(gptr, lptr)                                                      \
  __builtin_amdgcn_global_load_lds(                                            \
      (const __attribute__((address_space(1))) void*)(gptr),                   \
      (__attribute__((address_space(3))) void*)(uint32_t)(uintptr_t)(lptr),    \
      16, 0, 0)

// 4-stage in-register Hadamard butterfly on 16 elements (unnormalized).
__device__ __forceinline__ void fht16(float v[16]) {
#pragma unroll
  for (int h = 1; h < 16; h <<= 1) {
#pragma unroll
    for (int i = 0; i < 16; i += (h << 1)) {
#pragma unroll
      for (int j = 0; j < h; ++j) {
        float a = v[i + j], b = v[i + j + h];
        v[i + j] = a + b;
        v[i + j + h] = a - b;
      }
    }
  }
}

// Component-wise (4 independent transforms) butterfly on f32x4 lanes.
__device__ __forceinline__ void fht16v(f32x4 v[16]) {
#pragma unroll
  for (int h = 1; h < 16; h <<= 1) {
#pragma unroll
    for (int i = 0; i < 16; i += (h << 1)) {
#pragma unroll
      for (int j = 0; j < h; ++j) {
        f32x4 a = v[i + j], b = v[i + j + h];
        v[i + j] = a + b;
        v[i + j + h] = a - b;
      }
    }
  }
}

__device__ __forceinline__ void fht4(float& a, float& b, float& c, float& d) {
  float t0 = a + b, t1 = a - b, t2 = c + d, t3 = c - d;
  a = t0 + t2; b = t1 + t3; c = t0 - t2; d = t1 - t3;
}

// ---------------------------------------------------------------------------
// Kernel 1: x = f16( FHT(input*SU) * Wscale/64 ).  4 rows per block (256thr,
// wave = row plane).  LDS = 4 planes x 4096 fp32 (64KB), XOR-swizzled so all
// three phases are pure conflict-free ds_*_b128.
// ---------------------------------------------------------------------------
#define SWZ(c) ((c) ^ (((((c) >> 4) ^ ((c) >> 8)) & 7) << 2))

__global__ __launch_bounds__(256) void k_fht_in(const float* __restrict__ x,
                                                const float* __restrict__ SU,
                                                const float* __restrict__ wscale,
                                                f16* __restrict__ out) {
  __shared__ __attribute__((aligned(16))) float lds[4 * 4096];
  const int t = threadIdx.x;
  const int rw = t >> 6;  // wave index = row within the 4-row group
  const int u = t & 63;
  const size_t row = (size_t)blockIdx.x * 4 + rw;
  float* pl = &lds[rw << 12];  // this wave's row plane
  const float* xr = x + row * N_FEAT;

  // ---- phase 1: bits 0..3 over 4 groups of 16 consecutive cols ----
#pragma unroll
  for (int g = 0; g < 4; ++g) {
    const int c16 = (g << 10) + (u << 4);
    float v[16];
#pragma unroll
    for (int q = 0; q < 4; ++q) {
      const f32x4 a = *(const f32x4*)(xr + c16 + (q << 2));
      const f32x4 s4 = *(const f32x4*)(SU + c16 + (q << 2));
      const f32x4 m = a * s4;
      v[4 * q + 0] = m[0]; v[4 * q + 1] = m[1];
      v[4 * q + 2] = m[2]; v[4 * q + 3] = m[3];
    }
    fht16(v);
#pragma unroll
    for (int q = 0; q < 4; ++q) {
      const int col = c16 + (q << 2);
      f32x4 wv = {v[4 * q + 0], v[4 * q + 1], v[4 * q + 2], v[4 * q + 3]};
      *(f32x4*)&pl[SWZ(col)] = wv;
    }
  }
  __syncthreads();

  // ---- phase 2: bits 4..7, f32x4 over low cols a4..a4+3 ----
  {
    const int b = u >> 2, a4 = (u & 3) << 2;
    f32x4 v[16];
#pragma unroll
    for (int jj = 0; jj < 16; ++jj)
      v[jj] = *(const f32x4*)&pl[SWZ((b << 8) + (jj << 4) + a4)];
    fht16v(v);
#pragma unroll
    for (int jj = 0; jj < 16; ++jj)
      *(f32x4*)&pl[SWZ((b << 8) + (jj << 4) + a4)] = v[jj];
  }
  __syncthreads();

  // ---- phase 3: bits 8..11, f32x4 over cols q4..q4+3, scale, f16 store ----
  {
    const int q4 = u << 2;
    f32x4 v[16];
#pragma unroll
    for (int j = 0; j < 16; ++j)
      v[j] = *(const f32x4*)&pl[SWZ((j << 8) + q4)];
    fht16v(v);
    const float s = wscale[0] * 0.015625f;  // 1/sqrt(4096) = 1/64
    f16* op = out + row * N_FEAT;
#pragma unroll
    for (int j = 0; j < 16; ++j) {
      union { f16 h[4]; uint2 u2; } pk;
      pk.h[0] = (f16)(v[j][0] * s); pk.h[1] = (f16)(v[j][1] * s);
      pk.h[2] = (f16)(v[j][2] * s); pk.h[3] = (f16)(v[j][3] * s);
      *(uint2*)(op + (j << 8) + q4) = pk.u2;
    }
  }
}

// ---------------------------------------------------------------------------
// Kernel 2: pass A of W' = H*W — decode e8p codes, H64 over low 6 bits of n.
// ---------------------------------------------------------------------------
__global__ __launch_bounds__(256) void k_wA(const int* __restrict__ q,
                                            const float* __restrict__ grid,
                                            f16* __restrict__ Wp) {
  __shared__ float tabf[2048];
  __shared__ float tile[64 * 65];
  const int t = threadIdx.x;
  const int kg = blockIdx.x;
  const int ng = blockIdx.y;
  {
    *(float4*)&tabf[t * 8] = *(const float4*)(grid + t * 8);
    *(float4*)&tabf[t * 8 + 4] = *(const float4*)(grid + t * 8 + 4);
  }
  __syncthreads();

#pragma unroll
  for (int e2 = 0; e2 < 2; ++e2) {
    const int e = t + (e2 << 8);
    const int nl = e >> 3, c = e & 7;
    const unsigned code =
        (unsigned)q[(size_t)(ng * 64 + nl) * QSTRIDE + kg * 8 + c] & 0xffffu;
    const float* tb = &tabf[(code & 255u) * 8];
#pragma unroll
    for (int j = 0; j < 8; ++j) {
      const int bi = __float_as_int(tb[j]) ^ (int)(((code >> (8 + j)) & 1u) << 31);
      tile[nl * 65 + (c << 3) + j] = __int_as_float(bi);
    }
  }
  __syncthreads();

  {
    const int k = t & 63, p = t >> 6;
    float v[16];
#pragma unroll
    for (int j = 0; j < 16; ++j) v[j] = tile[(16 * p + j) * 65 + k];
    fht16(v);
#pragma unroll
    for (int j = 0; j < 16; ++j) tile[(16 * p + j) * 65 + k] = v[j];
  }
  __syncthreads();

  {
    const int k = t & 63, base = (t >> 6) << 2;
#pragma unroll
    for (int bb = 0; bb < 4; ++bb) {
      const int low = base + bb;
      float v0 = tile[(low) * 65 + k],      v1 = tile[(low + 16) * 65 + k];
      float v2 = tile[(low + 32) * 65 + k], v3 = tile[(low + 48) * 65 + k];
      fht4(v0, v1, v2, v3);
      tile[(low) * 65 + k] = v0;      tile[(low + 16) * 65 + k] = v1;
      tile[(low + 32) * 65 + k] = v2; tile[(low + 48) * 65 + k] = v3;
    }
  }
  __syncthreads();

  {
    const int nl = t >> 2, koff = (t & 3) << 4;
    union { f16 h[16]; int4 v[2]; } u;
#pragma unroll
    for (int i = 0; i < 16; ++i) u.h[i] = (f16)tile[nl * 65 + koff + i];
    int4* dst = (int4*)(Wp + (size_t)(ng * 64 + nl) * N_FEAT + kg * 64 + koff);
    dst[0] = u.v[0];
    dst[1] = u.v[1];
  }
}

// ---------------------------------------------------------------------------
// Kernel 3: pass B — H64 over n bits 6..11, in place on Wp.
// ---------------------------------------------------------------------------
__global__ __launch_bounds__(256) void k_wB(f16* __restrict__ Wp) {
  __shared__ float tile[64 * 65];
  const int t = threadIdx.x;
  const int kg = blockIdx.x;
  const int n0 = blockIdx.y;
  {
    const int n1 = t >> 2, koff = (t & 3) << 4;
    const f16* src = Wp + (size_t)(n0 + 64 * n1) * N_FEAT + kg * 64 + koff;
    union { f16 h[16]; int4 v[2]; } u;
    u.v[0] = ((const int4*)src)[0];
    u.v[1] = ((const int4*)src)[1];
#pragma unroll
    for (int i = 0; i < 16; ++i) tile[n1 * 65 + koff + i] = (float)u.h[i];
  }
  __syncthreads();
  {
    const int k = t & 63, p = t >> 6;
    float v[16];
#pragma unroll
    for (int j = 0; j < 16; ++j) v[j] = tile[(16 * p + j) * 65 + k];
    fht16(v);
#pragma unroll
    for (int j = 0; j < 16; ++j) tile[(16 * p + j) * 65 + k] = v[j];
  }
  __syncthreads();
  {
    const int k = t & 63, base = (t >> 6) << 2;
#pragma unroll
    for (int bb = 0; bb < 4; ++bb) {
      const int low = base + bb;
      float v0 = tile[(low) * 65 + k],      v1 = tile[(low + 16) * 65 + k];
      float v2 = tile[(low + 32) * 65 + k], v3 = tile[(low + 48) * 65 + k];
      fht4(v0, v1, v2, v3);
      tile[(low) * 65 + k] = v0;      tile[(low + 16) * 65 + k] = v1;
      tile[(low + 32) * 65 + k] = v2; tile[(low + 48) * 65 + k] = v3;
    }
  }
  __syncthreads();
  {
    const int n1 = t >> 2, koff = (t & 3) << 4;
    union { f16 h[16]; int4 v[2]; } u;
#pragma unroll
    for (int i = 0; i < 16; ++i) u.h[i] = (f16)tile[n1 * 65 + koff + i];
    int4* dst = (int4*)(Wp + (size_t)(n0 + 64 * n1) * N_FEAT + kg * 64 + koff);
    dst[0] = u.v[0];
    dst[1] = u.v[1];
  }
}

// ---------------------------------------------------------------------------
// Kernel 4: out[8192,4096](fp32) = (x * W'^T)/64 * SV + bias.
// 256x256 tile, BK=64, 8 waves (2Mx4N).  Round-5 structure: A staged via
// global_load_lds into LDS (swizzled), B fragments loaded DIRECT global->reg
// (double-buffered bA/bB) — removes B from LDS entirely.  LDS per K-tile
// drops 256KB -> 160KB (< MFMA 640cyc), lifting the LDS-BW ceiling.
//
// Per-iteration vmem issue order (pinned by fences; 12 ops/wave):
//   I1: 2 gldA-lo(t+1) | I2: 8 gldB(t+1) | I3: 2 gldA-hi(t+1)
// Wait bookkeeping (outstanding per wave; induction verified):
//   enter t: [B(t) 8, aHi(t) 2] = 10
//   step1 I1(t+1)            -> 12
//   step3 vmcnt(4): B(t) retired -> bcur usable; MFMA mh=0 (32)
//   step4 I2(t+1)            -> 12
//   step5 vmcnt(10)+barrier: aHi(t) retired -> sA[cur] hi visible
//   step6 LDA(af,1); MFMA mh=1 (32)
//   step7 I3(t+1)            -> 12
//   step8 vmcnt(10)+barrier: aLo(t+1) retired -> next P1 readable; -> 10
// WAR safety: all sA[cur] reads are lgkm-drained by their consuming MFMAs
// before each wave's step-8 barrier; overwrites issue only after it.
// B values identical to the staged path: staging swizzle cancels, frag =
// B[n][k0 + 32s + 8*quad], loaded here directly.
// ---------------------------------------------------------------------------
#define BM 256
#define BN 256
#define BK 64
#define KDIM 4096

#define SCHED_FENCE() __builtin_amdgcn_sched_barrier(0)

// Stage one 128-row x 64-k half of A: wave w covers rows w*16+i*8..+7.
#define STAGE_HALF(gbase, lhalf)                                         \
  {                                                                      \
    _Pragma("unroll")                                                    \
    for (int i_ = 0; i_ < 2; ++i_) {                                     \
      const int rb_ = (w << 4) + (i_ << 3);                              \
      const int r_ = rb_ + srow;                                         \
      const int kc_ = scc ^ (r_ & 7);                                    \
      GLD16((gbase) + (size_t)r_ * KDIM + (kc_ << 3), (lhalf) + (rb_ << 6)); \
    }                                                                    \
  }

// A-fragments: 4 m-frags x 2 k-steps from m-half mh of buffer cur.
#define LDA(dst, mh, cur)                                                \
  {                                                                      \
    _Pragma("unroll")                                                    \
    for (int i_ = 0; i_ < 4; ++i_) {                                     \
      const int m_ = ((mh) << 7) + (wr << 6) + (i_ << 4) + ml;           \
      _Pragma("unroll")                                                  \
      for (int s_ = 0; s_ < 2; ++s_) {                                   \
        const int kc_ = ((s_ << 2) + quad) ^ (m_ & 7);                   \
        dst[i_][s_] = *(const f16x8*)&sA[cur][(m_ << 6) + (kc_ << 3)];   \
      }                                                                  \
    }                                                                    \
  }

// B fragments direct global->reg: 4 n-frags x 2 k-steps (8 b128 loads).
#define LOADB(dst, kbase)                                                \
  {                                                                      \
    _Pragma("unroll")                                                    \
    for (int nj_ = 0; nj_ < 4; ++nj_) {                                  \
      const int n_ = ((nj_ >> 1) << 7) + (wc << 5) + ((nj_ & 1) << 4) + ml; \
      const f16* bp_ = Bb + (size_t)n_ * KDIM + (kbase) + (quad << 3);   \
      dst[nj_][0] = *(const f16x8*)(bp_);                                \
      dst[nj_][1] = *(const f16x8*)(bp_ + 32);                           \
    }                                                                    \
  }

// One m-half against all 4 n-frags: 32 MFMA, setprio-wrapped.
#define MMAQ2(mh, b)                                                     \
  {                                                                      \
    __builtin_amdgcn_s_setprio(1);                                       \
    _Pragma("unroll")                                                    \
    for (int i_ = 0; i_ < 4; ++i_) {                                     \
      _Pragma("unroll")                                                  \
      for (int nj_ = 0; nj_ < 4; ++nj_) {                                \
        acc[(mh) * 4 + i_][nj_] =                                        \
            __builtin_amdgcn_mfma_f32_16x16x32_f16(                      \
                af[i_][0], b[nj_][0], acc[(mh) * 4 + i_][nj_], 0, 0, 0); \
        acc[(mh) * 4 + i_][nj_] =                                        \
            __builtin_amdgcn_mfma_f32_16x16x32_f16(                      \
                af[i_][1], b[nj_][1], acc[(mh) * 4 + i_][nj_], 0, 0, 0); \
      }                                                                  \
    }                                                                    \
    __builtin_amdgcn_s_setprio(0);                                       \
  }

// One K-tile iteration; bcur/bnxt are statically-named register frag sets.
#define GBODY(bcur, bnxt, tt)                                            \
  {                                                                      \
    const int cur_ = (tt) & 1;                                           \
    const int nxt_ = cur_ ^ 1;                                           \
    const int kn_ = (((tt) + 1) & 63) << 6; /* wrap-stage tile 0 */      \
    const f16* An_ = Ab + kn_;                                           \
    STAGE_HALF(An_, &sA[nxt_][0]);                         /* I1 */      \
    SCHED_FENCE();                                                       \
    LDA(af, 0, cur_);                                                    \
    asm volatile("s_waitcnt vmcnt(4)" ::: "memory");       /* B(t) ok */ \
    MMAQ2(0, bcur);                                                      \
    LOADB(bnxt, kn_);                                      /* I2 */      \
    SCHED_FENCE();                                                       \
    asm volatile("s_waitcnt vmcnt(10)" ::: "memory");      /* aHi(t) */  \
    __builtin_amdgcn_s_barrier();                                        \
    LDA(af, 1, cur_);                                                    \
    MMAQ2(1, bcur);                                                      \
    STAGE_HALF(An_ + (size_t)128 * KDIM, &sA[nxt_][128 * 64]); /* I3 */  \
    SCHED_FENCE();                                                       \
    asm volatile("s_waitcnt vmcnt(10)" ::: "memory");      /* aLo(t+1)*/ \
    __builtin_amdgcn_s_barrier();                                        \
  }

__global__ __launch_bounds__(512, 2) void k_gemm(const f16* __restrict__ A,
                                                 const f16* __restrict__ B,
                                                 float* __restrict__ C,
                                                 const float* __restrict__ SV,
                                                 const float* __restrict__ bias) {
  __shared__ __attribute__((aligned(16))) f16 sA[2][BM * BK];

  const int tid = threadIdx.x;
  const int lane = tid & 63;
  const int w = tid >> 6;        // 0..7
  const int wr = w >> 2;         // 0..1 : 64-row band within each m-half
  const int wc = w & 3;          // 0..3 : 32-col band within each n-half

  // XCD-chunked bijective swizzle (neutral on counters but harmless).
  const int lin = blockIdx.y * gridDim.x + blockIdx.x;  // dispatch order
  const int swz = ((lin & 7) << 6) | (lin >> 3);        // nwg=512, bijective
  const int m0 = (swz >> 4) * BM;
  const int n0 = (swz & 15) * BN;

  const int quad = lane >> 4;
  const int ml = lane & 15;
  const int srow = lane >> 3;    // staging: row within 8-row group
  const int scc = lane & 7;      // staging: chunk (pre-swizzled at source)

  f32x4 acc[8][4];
#pragma unroll
  for (int i = 0; i < 8; ++i)
#pragma unroll
    for (int j = 0; j < 4; ++j) acc[i][j] = (f32x4)0.0f;

  const f16* Ab = A + (size_t)m0 * KDIM;
  const f16* Bb = B + (size_t)n0 * KDIM;

  f16x8 af[4][2], bA[4][2], bB[4][2];

  // Prologue: issue [aLo(0) 2, B(0) 8, aHi(0) 2]; retire aLo(0).
  STAGE_HALF(Ab, &sA[0][0]);
  SCHED_FENCE();
  LOADB(bA, 0);
  SCHED_FENCE();
  STAGE_HALF(Ab + (size_t)128 * KDIM, &sA[0][128 * 64]);
  SCHED_FENCE();
  asm volatile("s_waitcnt vmcnt(10)" ::: "memory");
  __builtin_amdgcn_s_barrier();  // sA[0] lo visible; enter with 10 in flight

  for (int t2 = 0; t2 < 32; ++t2) {
    GBODY(bA, bB, 2 * t2);
    GBODY(bB, bA, 2 * t2 + 1);
  }

  // Drain wrap-staged loads before LDS goes out of scope at endpgm.
  asm volatile("s_waitcnt vmcnt(0)" ::: "memory");

  // ---- epilogue: out = acc*(SV/64) + bias, fp32 stores ----
#pragma unroll
  for (int nj = 0; nj < 4; ++nj) {
    const int col = n0 + ((nj >> 1) << 7) + (wc << 5) + ((nj & 1) << 4) + ml;
    const float sv = SV[col] * 0.015625f;
    const float bs = bias[col];
#pragma unroll
    for (int mi = 0; mi < 8; ++mi) {
      const int rowb =
          m0 + ((mi >> 2) << 7) + (wr << 6) + ((mi & 3) << 4) + (quad << 2);
#pragma unroll
      for (int r = 0; r < 4; ++r)
        C[(size_t)(rowb + r) * N_FEAT + col] = acc[mi][nj][r] * sv + bs;
    }
  }
}

// ---------------------------------------------------------------------------
// Host. Buffer plan:
//   d_ws[0, 64MB)          : x (f16)   — written by fht_in, read by gemm
//   W' (f16, 32MB)         : d_ws[64MB,96MB) when ws_size permits (keeps
//                            d_in pristine); else reuse the input buffer
//                            (stream-ordered after fht_in consumed it).
//   d_out                  : final fp32 output, written only by gemm.
// ---------------------------------------------------------------------------
extern "C" void kernel_launch(void* const* d_in, const int* in_sizes, int n_in,
                              void* d_out, int out_size, void* d_ws, size_t ws_size,
                              hipStream_t stream) {
  const float* input = nullptr;
  const int* qidxs = nullptr;
  const float* grid_abs = nullptr;
  const float* wscale = nullptr;
  const float* v4k[3] = {nullptr, nullptr, nullptr};
  int n4 = 0;
  for (int i = 0; i < n_in; ++i) {
    switch (in_sizes[i]) {
      case 33554432: input = (const float*)d_in[i]; break;
      case 2097152:  qidxs = (const int*)d_in[i]; break;
      case 2048:     grid_abs = (const float*)d_in[i]; break;
      case 1:        wscale = (const float*)d_in[i]; break;
      case 4096:     if (n4 < 3) v4k[n4++] = (const float*)d_in[i]; break;
      default: break;
    }
  }
  const float* SU = v4k[0];
  const float* SV = v4k[1];
  const float* bias = v4k[2];

  f16* x = (f16*)d_ws;
  f16* Wp;
  if (ws_size >= (size_t)100663296) {       // 96 MiB: room for x + W'
    Wp = (f16*)((char*)d_ws + 67108864);    // keep input buffer pristine
  } else {
    Wp = (f16*)const_cast<float*>(input);   // reuse input buffer post-FHT
  }
  float* out = (float*)d_out;

  k_fht_in<<<M_ROWS / 4, 256, 0, stream>>>(input, SU, wscale, x);
  dim3 gw(64, 64);
  k_wA<<<gw, 256, 0, stream>>>(qidxs, grid_abs, Wp);
  k_wB<<<gw, 256, 0, stream>>>(Wp);
  dim3 g(N_FEAT / BN, M_ROWS / BM);
  k_gemm<<<g, 512, 0, stream>>>(x, Wp, out, SV, bias);
}

// Round 6
// 539.812 us; speedup vs baseline: 1.1971x; 1.1971x over previous
//
#include <hip/hip_runtime.h>
#include <hip/hip_bf16.h>
#include <stdint.h>

typedef _Float16 f16;
typedef _Float16 f16x8 __attribute__((ext_vector_type(8)));
typedef float f32x4 __attribute__((ext_vector_type(4)));

#define N_FEAT 4096
#define M_ROWS 8192
#define QSTRIDE 512  // IN_FEATURES / 8 codewords per W row

// Async global->LDS, 16B per lane: wave-uniform LDS base, HW adds lane*16.
#define GLD16(gptr, lptr)                                                      \
  __builtin_amdgcn_global_load_lds(                                            \
      (const __attribute__((address_space(1))) void*)(gptr),                   \
      (__attribute__((address_space(3))) void*)(uint32_t)(uintptr_t)(lptr),    \
      16, 0, 0)

// 4-stage in-register Hadamard butterfly on 16 elements (unnormalized).
__device__ __forceinline__ void fht16(float v[16]) {
#pragma unroll
  for (int h = 1; h < 16; h <<= 1) {
#pragma unroll
    for (int i = 0; i < 16; i += (h << 1)) {
#pragma unroll
      for (int j = 0; j < h; ++j) {
        float a = v[i + j], b = v[i + j + h];
        v[i + j] = a + b;
        v[i + j + h] = a - b;
      }
    }
  }
}

// Component-wise (4 independent transforms) butterfly on f32x4 lanes.
__device__ __forceinline__ void fht16v(f32x4 v[16]) {
#pragma unroll
  for (int h = 1; h < 16; h <<= 1) {
#pragma unroll
    for (int i = 0; i < 16; i += (h << 1)) {
#pragma unroll
      for (int j = 0; j < h; ++j) {
        f32x4 a = v[i + j], b = v[i + j + h];
        v[i + j] = a + b;
        v[i + j + h] = a - b;
      }
    }
  }
}

__device__ __forceinline__ void fht4(float& a, float& b, float& c, float& d) {
  float t0 = a + b, t1 = a - b, t2 = c + d, t3 = c - d;
  a = t0 + t2; b = t1 + t3; c = t0 - t2; d = t1 - t3;
}

// ---------------------------------------------------------------------------
// Kernel 1: x = f16( FHT(input*SU) * Wscale/64 ).  4 rows per block (256thr,
// wave = row plane).  LDS = 4 planes x 4096 fp32 (64KB), XOR-swizzled so all
// three phases are pure conflict-free ds_*_b128.
// ---------------------------------------------------------------------------
#define SWZ(c) ((c) ^ (((((c) >> 4) ^ ((c) >> 8)) & 7) << 2))

__global__ __launch_bounds__(256) void k_fht_in(const float* __restrict__ x,
                                                const float* __restrict__ SU,
                                                const float* __restrict__ wscale,
                                                f16* __restrict__ out) {
  __shared__ __attribute__((aligned(16))) float lds[4 * 4096];
  const int t = threadIdx.x;
  const int rw = t >> 6;  // wave index = row within the 4-row group
  const int u = t & 63;
  const size_t row = (size_t)blockIdx.x * 4 + rw;
  float* pl = &lds[rw << 12];  // this wave's row plane
  const float* xr = x + row * N_FEAT;

  // ---- phase 1: bits 0..3 over 4 groups of 16 consecutive cols ----
#pragma unroll
  for (int g = 0; g < 4; ++g) {
    const int c16 = (g << 10) + (u << 4);
    float v[16];
#pragma unroll
    for (int q = 0; q < 4; ++q) {
      const f32x4 a = *(const f32x4*)(xr + c16 + (q << 2));
      const f32x4 s4 = *(const f32x4*)(SU + c16 + (q << 2));
      const f32x4 m = a * s4;
      v[4 * q + 0] = m[0]; v[4 * q + 1] = m[1];
      v[4 * q + 2] = m[2]; v[4 * q + 3] = m[3];
    }
    fht16(v);
#pragma unroll
    for (int q = 0; q < 4; ++q) {
      const int col = c16 + (q << 2);
      f32x4 wv = {v[4 * q + 0], v[4 * q + 1], v[4 * q + 2], v[4 * q + 3]};
      *(f32x4*)&pl[SWZ(col)] = wv;
    }
  }
  __syncthreads();

  // ---- phase 2: bits 4..7, f32x4 over low cols a4..a4+3 ----
  {
    const int b = u >> 2, a4 = (u & 3) << 2;
    f32x4 v[16];
#pragma unroll
    for (int jj = 0; jj < 16; ++jj)
      v[jj] = *(const f32x4*)&pl[SWZ((b << 8) + (jj << 4) + a4)];
    fht16v(v);
#pragma unroll
    for (int jj = 0; jj < 16; ++jj)
      *(f32x4*)&pl[SWZ((b << 8) + (jj << 4) + a4)] = v[jj];
  }
  __syncthreads();

  // ---- phase 3: bits 8..11, f32x4 over cols q4..q4+3, scale, f16 store ----
  {
    const int q4 = u << 2;
    f32x4 v[16];
#pragma unroll
    for (int j = 0; j < 16; ++j)
      v[j] = *(const f32x4*)&pl[SWZ((j << 8) + q4)];
    fht16v(v);
    const float s = wscale[0] * 0.015625f;  // 1/sqrt(4096) = 1/64
    f16* op = out + row * N_FEAT;
#pragma unroll
    for (int j = 0; j < 16; ++j) {
      union { f16 h[4]; uint2 u2; } pk;
      pk.h[0] = (f16)(v[j][0] * s); pk.h[1] = (f16)(v[j][1] * s);
      pk.h[2] = (f16)(v[j][2] * s); pk.h[3] = (f16)(v[j][3] * s);
      *(uint2*)(op + (j << 8) + q4) = pk.u2;
    }
  }
}

// ---------------------------------------------------------------------------
// Kernel 2 (k_w1): decode e8p codes + H64 over n bits 6..11 (strided rows
// n = ng + 64*n1).  Row-major write to Wtmp.  (Pass order vs the previous
// version is swapped; Hadamard stages commute, rounding-only difference.)
// ---------------------------------------------------------------------------
__global__ __launch_bounds__(256) void k_w1(const int* __restrict__ q,
                                            const float* __restrict__ grid,
                                            f16* __restrict__ Wtmp) {
  __shared__ float tabf[2048];
  __shared__ float tile[64 * 65];
  const int t = threadIdx.x;
  const int kg = blockIdx.x;
  const int ng = blockIdx.y;  // rows ng + 64*n1
  {
    *(float4*)&tabf[t * 8] = *(const float4*)(grid + t * 8);
    *(float4*)&tabf[t * 8 + 4] = *(const float4*)(grid + t * 8 + 4);
  }
  __syncthreads();

#pragma unroll
  for (int e2 = 0; e2 < 2; ++e2) {
    const int e = t + (e2 << 8);
    const int nl = e >> 3, c = e & 7;
    const unsigned code =
        (unsigned)q[(size_t)(ng + 64 * nl) * QSTRIDE + kg * 8 + c] & 0xffffu;
    const float* tb = &tabf[(code & 255u) * 8];
#pragma unroll
    for (int j = 0; j < 8; ++j) {
      const int bi = __float_as_int(tb[j]) ^ (int)(((code >> (8 + j)) & 1u) << 31);
      tile[nl * 65 + (c << 3) + j] = __int_as_float(bi);
    }
  }
  __syncthreads();

  {  // H16 over nl bits 0..3  (global n bits 6..9)
    const int k = t & 63, p = t >> 6;
    float v[16];
#pragma unroll
    for (int j = 0; j < 16; ++j) v[j] = tile[(16 * p + j) * 65 + k];
    fht16(v);
#pragma unroll
    for (int j = 0; j < 16; ++j) tile[(16 * p + j) * 65 + k] = v[j];
  }
  __syncthreads();

  {  // H4 over nl bits 4..5  (global n bits 10..11)
    const int k = t & 63, base = (t >> 6) << 2;
#pragma unroll
    for (int bb = 0; bb < 4; ++bb) {
      const int low = base + bb;
      float v0 = tile[(low) * 65 + k],      v1 = tile[(low + 16) * 65 + k];
      float v2 = tile[(low + 32) * 65 + k], v3 = tile[(low + 48) * 65 + k];
      fht4(v0, v1, v2, v3);
      tile[(low) * 65 + k] = v0;      tile[(low + 16) * 65 + k] = v1;
      tile[(low + 32) * 65 + k] = v2; tile[(low + 48) * 65 + k] = v3;
    }
  }
  __syncthreads();

  {  // row-major write (coalesced 32B/thread)
    const int n1 = t >> 2, koff = (t & 3) << 4;
    union { f16 h[16]; int4 v[2]; } u;
#pragma unroll
    for (int i = 0; i < 16; ++i) u.h[i] = (f16)tile[n1 * 65 + koff + i];
    int4* dst = (int4*)(Wtmp + (size_t)(ng + 64 * n1) * N_FEAT + kg * 64 + koff);
    dst[0] = u.v[0];
    dst[1] = u.v[1];
  }
}

// ---------------------------------------------------------------------------
// Kernel 3 (k_w2): H64 over n bits 0..5 on 64 CONSECUTIVE rows, then write
// W' in MFMA FRAGMENT layout:
//   Wf[((ntile*128 + k32)*64 + lane)*8 + j] = W'[ntile*16 + (lane&15)]
//                                               [k32*32 + (lane>>4)*8 + j]
// Each (ntile,k32) chunk is 1KB contiguous, written by one 64-thread group
// -> fully coalesced; gemm reads it back with base + lane*16B.
// ---------------------------------------------------------------------------
__global__ __launch_bounds__(256) void k_w2(const f16* __restrict__ Wtmp,
                                            f16* __restrict__ Wf) {
  __shared__ float tile[64 * 65];
  const int t = threadIdx.x;
  const int kg = blockIdx.x;
  const int ng = blockIdx.y;  // rows ng*64 .. +63
  {
    const int n1 = t >> 2, koff = (t & 3) << 4;
    const f16* src = Wtmp + (size_t)(ng * 64 + n1) * N_FEAT + kg * 64 + koff;
    union { f16 h[16]; int4 v[2]; } u;
    u.v[0] = ((const int4*)src)[0];
    u.v[1] = ((const int4*)src)[1];
#pragma unroll
    for (int i = 0; i < 16; ++i) tile[n1 * 65 + koff + i] = (float)u.h[i];
  }
  __syncthreads();
  {  // H16 over n bits 0..3
    const int k = t & 63, p = t >> 6;
    float v[16];
#pragma unroll
    for (int j = 0; j < 16; ++j) v[j] = tile[(16 * p + j) * 65 + k];
    fht16(v);
#pragma unroll
    for (int j = 0; j < 16; ++j) tile[(16 * p + j) * 65 + k] = v[j];
  }
  __syncthreads();
  {  // H4 over n bits 4..5
    const int k = t & 63, base = (t >> 6) << 2;
#pragma unroll
    for (int bb = 0; bb < 4; ++bb) {
      const int low = base + bb;
      float v0 = tile[(low) * 65 + k],      v1 = tile[(low + 16) * 65 + k];
      float v2 = tile[(low + 32) * 65 + k], v3 = tile[(low + 48) * 65 + k];
      fht4(v0, v1, v2, v3);
      tile[(low) * 65 + k] = v0;      tile[(low + 16) * 65 + k] = v1;
      tile[(low + 32) * 65 + k] = v2; tile[(low + 48) * 65 + k] = v3;
    }
  }
  __syncthreads();
  {  // fragment-layout epilogue: 4 local ntiles x 2 k32 chunks
    const int cp = t >> 6;          // wave = local ntile 0..3
    const int lane = t & 63;
    const int ml = lane & 15, qd = lane >> 4;
    const int nl = (cp << 4) + ml;
#pragma unroll
    for (int k32l = 0; k32l < 2; ++k32l) {
      const int kl = (k32l << 5) + (qd << 3);
      union { f16 h[8]; int4 v; } u;
#pragma unroll
      for (int j = 0; j < 8; ++j) u.h[j] = (f16)tile[nl * 65 + kl + j];
      const size_t ntile = (size_t)((ng << 2) + cp);
      const size_t k32 = (size_t)((kg << 1) + k32l);
      *(int4*)(Wf + ((ntile * 128 + k32) * 64 + lane) * 8) = u.v;
    }
  }
}

// ---------------------------------------------------------------------------
// Kernel 4: out[8192,4096](fp32) = (x * W'^T)/64 * SV + bias.
// 256x256 tile, BK=64, 8 waves (2Mx4N).  A staged via global_load_lds into
// LDS (swizzled, 64KB dbuf); B fragments DIRECT global->reg from the
// fragment-layout Wf (coalesced 1KB per load).  LDS traffic/K-tile:
// 32KB write + 128KB read = 160KB (~625cyc) vs MFMA 620cyc -> MFMA-bound.
// Schedule identical to the correctness-verified round-5 one (absmax 4.0);
// only LOADB addressing changed.
//
// Per-iteration vmem issue order (pinned by fences; 12 ops/wave):
//   I1: 2 gldA-lo(t+1) | I2: 8 loadB(t+1) | I3: 2 gldA-hi(t+1)
// Wait bookkeeping (outstanding per wave; induction verified):
//   enter t: [B(t) 8, aHi(t) 2] = 10
//   I1(t+1)                  -> 12
//   vmcnt(4): B(t) retired -> bcur usable; MFMA mh=0 (32)
//   I2(t+1)                  -> 12
//   vmcnt(10)+barrier: aHi(t) retired -> sA[cur] hi visible
//   LDA(af,1); MFMA mh=1 (32)
//   I3(t+1)                  -> 12
//   vmcnt(10)+barrier: aLo(t+1) retired -> next iter P1 readable; -> 10
// ---------------------------------------------------------------------------
#define BM 256
#define BN 256
#define BK 64
#define KDIM 4096

#define SCHED_FENCE() __builtin_amdgcn_sched_barrier(0)

// Stage one 128-row x 64-k half of A: wave w covers rows w*16+i*8..+7.
#define STAGE_HALF(gbase, lhalf)                                         \
  {                                                                      \
    _Pragma("unroll")                                                    \
    for (int i_ = 0; i_ < 2; ++i_) {                                     \
      const int rb_ = (w << 4) + (i_ << 3);                              \
      const int r_ = rb_ + srow;                                         \
      const int kc_ = scc ^ (r_ & 7);                                    \
      GLD16((gbase) + (size_t)r_ * KDIM + (kc_ << 3), (lhalf) + (rb_ << 6)); \
    }                                                                    \
  }

// A-fragments: 4 m-frags x 2 k-steps from m-half mh of buffer cur.
#define LDA(dst, mh, cur)                                                \
  {                                                                      \
    _Pragma("unroll")                                                    \
    for (int i_ = 0; i_ < 4; ++i_) {                                     \
      const int m_ = ((mh) << 7) + (wr << 6) + (i_ << 4) + ml;           \
      _Pragma("unroll")                                                  \
      for (int s_ = 0; s_ < 2; ++s_) {                                   \
        const int kc_ = ((s_ << 2) + quad) ^ (m_ & 7);                   \
        dst[i_][s_] = *(const f16x8*)&sA[cur][(m_ << 6) + (kc_ << 3)];   \
      }                                                                  \
    }                                                                    \
  }

// B fragments direct global->reg from fragment layout: 8 coalesced 16B/lane
// loads (1KB/wave each).  frag(nj,s) lane = B[ntile*16+ml][k + s*32 + quad*8].
#define LOADB(dst, kbase)                                                \
  {                                                                      \
    _Pragma("unroll")                                                    \
    for (int nj_ = 0; nj_ < 4; ++nj_) {                                  \
      const int nc_ = n0 + ((nj_ >> 1) << 7) + (wc << 5) + ((nj_ & 1) << 4); \
      const f16* bp_ =                                                   \
          B + (((size_t)(nc_ >> 4) * 128 + ((kbase) >> 5)) * 64 + lane) * 8; \
      dst[nj_][0] = *(const f16x8*)(bp_);                                \
      dst[nj_][1] = *(const f16x8*)(bp_ + 512);                          \
    }                                                                    \
  }

// One m-half against all 4 n-frags: 32 MFMA, setprio-wrapped.
#define MMAQ2(mh, b)                                                     \
  {                                                                      \
    __builtin_amdgcn_s_setprio(1);                                       \
    _Pragma("unroll")                                                    \
    for (int i_ = 0; i_ < 4; ++i_) {                                     \
      _Pragma("unroll")                                                  \
      for (int nj_ = 0; nj_ < 4; ++nj_) {                                \
        acc[(mh) * 4 + i_][nj_] =                                        \
            __builtin_amdgcn_mfma_f32_16x16x32_f16(                      \
                af[i_][0], b[nj_][0], acc[(mh) * 4 + i_][nj_], 0, 0, 0); \
        acc[(mh) * 4 + i_][nj_] =                                        \
            __builtin_amdgcn_mfma_f32_16x16x32_f16(                      \
                af[i_][1], b[nj_][1], acc[(mh) * 4 + i_][nj_], 0, 0, 0); \
      }                                                                  \
    }                                                                    \
    __builtin_amdgcn_s_setprio(0);                                       \
  }

// One K-tile iteration; bcur/bnxt are statically-named register frag sets.
#define GBODY(bcur, bnxt, tt)                                            \
  {                                                                      \
    const int cur_ = (tt) & 1;                                           \
    const int nxt_ = cur_ ^ 1;                                           \
    const int kn_ = (((tt) + 1) & 63) << 6; /* wrap-stage tile 0 */      \
    const f16* An_ = Ab + kn_;                                           \
    STAGE_HALF(An_, &sA[nxt_][0]);                         /* I1 */      \
    SCHED_FENCE();                                                       \
    LDA(af, 0, cur_);                                                    \
    asm volatile("s_waitcnt vmcnt(4)" ::: "memory");       /* B(t) ok */ \
    MMAQ2(0, bcur);                                                      \
    LOADB(bnxt, kn_);                                      /* I2 */      \
    SCHED_FENCE();                                                       \
    asm volatile("s_waitcnt vmcnt(10)" ::: "memory");      /* aHi(t) */  \
    __builtin_amdgcn_s_barrier();                                        \
    LDA(af, 1, cur_);                                                    \
    MMAQ2(1, bcur);                                                      \
    STAGE_HALF(An_ + (size_t)128 * KDIM, &sA[nxt_][128 * 64]); /* I3 */  \
    SCHED_FENCE();                                                       \
    asm volatile("s_waitcnt vmcnt(10)" ::: "memory");      /* aLo(t+1)*/ \
    __builtin_amdgcn_s_barrier();                                        \
  }

__global__ __launch_bounds__(512, 2) void k_gemm(const f16* __restrict__ A,
                                                 const f16* __restrict__ B,
                                                 float* __restrict__ C,
                                                 const float* __restrict__ SV,
                                                 const float* __restrict__ bias) {
  __shared__ __attribute__((aligned(16))) f16 sA[2][BM * BK];

  const int tid = threadIdx.x;
  const int lane = tid & 63;
  const int w = tid >> 6;        // 0..7
  const int wr = w >> 2;         // 0..1 : 64-row band within each m-half
  const int wc = w & 3;          // 0..3 : 32-col band within each n-half

  // XCD-chunked bijective swizzle (neutral on counters but harmless).
  const int lin = blockIdx.y * gridDim.x + blockIdx.x;  // dispatch order
  const int swz = ((lin & 7) << 6) | (lin >> 3);        // nwg=512, bijective
  const int m0 = (swz >> 4) * BM;
  const int n0 = (swz & 15) * BN;

  const int quad = lane >> 4;
  const int ml = lane & 15;
  const int srow = lane >> 3;    // staging: row within 8-row group
  const int scc = lane & 7;      // staging: chunk (pre-swizzled at source)

  f32x4 acc[8][4];
#pragma unroll
  for (int i = 0; i < 8; ++i)
#pragma unroll
    for (int j = 0; j < 4; ++j) acc[i][j] = (f32x4)0.0f;

  const f16* Ab = A + (size_t)m0 * KDIM;

  f16x8 af[4][2], bA[4][2], bB[4][2];

  // Prologue: issue [aLo(0) 2, B(0) 8, aHi(0) 2]; retire aLo(0).
  STAGE_HALF(Ab, &sA[0][0]);
  SCHED_FENCE();
  LOADB(bA, 0);
  SCHED_FENCE();
  STAGE_HALF(Ab + (size_t)128 * KDIM, &sA[0][128 * 64]);
  SCHED_FENCE();
  asm volatile("s_waitcnt vmcnt(10)" ::: "memory");
  __builtin_amdgcn_s_barrier();  // sA[0] lo visible; enter with 10 in flight

  for (int t2 = 0; t2 < 32; ++t2) {
    GBODY(bA, bB, 2 * t2);
    GBODY(bB, bA, 2 * t2 + 1);
  }

  // Drain wrap-staged loads before LDS goes out of scope at endpgm.
  asm volatile("s_waitcnt vmcnt(0)" ::: "memory");

  // ---- epilogue: out = acc*(SV/64) + bias, fp32 stores ----
#pragma unroll
  for (int nj = 0; nj < 4; ++nj) {
    const int col = n0 + ((nj >> 1) << 7) + (wc << 5) + ((nj & 1) << 4) + ml;
    const float sv = SV[col] * 0.015625f;
    const float bs = bias[col];
#pragma unroll
    for (int mi = 0; mi < 8; ++mi) {
      const int rowb =
          m0 + ((mi >> 2) << 7) + (wr << 6) + ((mi & 3) << 4) + (quad << 2);
#pragma unroll
      for (int r = 0; r < 4; ++r)
        C[(size_t)(rowb + r) * N_FEAT + col] = acc[mi][nj][r] * sv + bs;
    }
  }
}

// ---------------------------------------------------------------------------
// Host. Buffer plan:
//   d_ws[0, 64MB)   : x (f16)            — fht_in -> gemm A
//   d_ws[64, 96MB)  : Wf fragment layout — w2 -> gemm B (fallback: input buf)
//   d_out           : 128MB fp32 out; first 32MB doubles as W' row-major
//                     SCRATCH between w1 and w2 (gemm fully overwrites out).
// ---------------------------------------------------------------------------
extern "C" void kernel_launch(void* const* d_in, const int* in_sizes, int n_in,
                              void* d_out, int out_size, void* d_ws, size_t ws_size,
                              hipStream_t stream) {
  const float* input = nullptr;
  const int* qidxs = nullptr;
  const float* grid_abs = nullptr;
  const float* wscale = nullptr;
  const float* v4k[3] = {nullptr, nullptr, nullptr};
  int n4 = 0;
  for (int i = 0; i < n_in; ++i) {
    switch (in_sizes[i]) {
      case 33554432: input = (const float*)d_in[i]; break;
      case 2097152:  qidxs = (const int*)d_in[i]; break;
      case 2048:     grid_abs = (const float*)d_in[i]; break;
      case 1:        wscale = (const float*)d_in[i]; break;
      case 4096:     if (n4 < 3) v4k[n4++] = (const float*)d_in[i]; break;
      default: break;
    }
  }
  const float* SU = v4k[0];
  const float* SV = v4k[1];
  const float* bias = v4k[2];

  f16* x = (f16*)d_ws;
  f16* Wtmp = (f16*)d_out;  // 32MB scratch inside the 128MB out buffer
  f16* Wf;
  if (ws_size >= (size_t)100663296) {       // 96 MiB: room for x + Wf
    Wf = (f16*)((char*)d_ws + 67108864);    // keep input buffer pristine
  } else {
    Wf = (f16*)const_cast<float*>(input);   // reuse input buffer post-FHT
  }
  float* out = (float*)d_out;

  k_fht_in<<<M_ROWS / 4, 256, 0, stream>>>(input, SU, wscale, x);
  dim3 gw(64, 64);
  k_w1<<<gw, 256, 0, stream>>>(qidxs, grid_abs, Wtmp);
  k_w2<<<gw, 256, 0, stream>>>(Wtmp, Wf);
  dim3 g(N_FEAT / BN, M_ROWS / BM);
  k_gemm<<<g, 512, 0, stream>>>(x, Wf, out, SV, bias);
}